// Round 2
// baseline (1150.041 us; speedup 1.0000x reference)
//
#include <hip/hip_runtime.h>
#include <hip/hip_bf16.h>

#define BB 2
#define NN 256
#define DD 128
#define TDD 64
#define LL 4
#define NGROUP 32
#define NROWS (BB*NN*NN)      // 131072 edge rows
#define LDS_STR 68            // padded LDS stride (dwords), 16B aligned, bank-spread

#define LOG1E4 9.210340371976184f
#define TWO_PI 6.283185307179586f

// ---------------- generic 64row x 128col tile GEMM inner loop ----------------
// AT: __shared__ float[128*LDS_STR], transposed A tile: AT[k*LDS_STR + row]
// WPTR: const float* row-major W[k*128 + c]
// tx = tid&31 (cols 4*tx..4*tx+3), ty = tid>>5 (rows 8*ty..8*ty+7)
#define TILE_GEMM(AT, WPTR, ACC) do {                                          \
  _Pragma("unroll 4")                                                          \
  for (int k = 0; k < 128; ++k) {                                              \
    const float4 w4 = *reinterpret_cast<const float4*>((WPTR) + k*128 + tx*4); \
    const float4 a0 = *reinterpret_cast<const float4*>(&(AT)[k*LDS_STR + ty*8]);     \
    const float4 a1 = *reinterpret_cast<const float4*>(&(AT)[k*LDS_STR + ty*8 + 4]); \
    const float av[8] = {a0.x,a0.y,a0.z,a0.w,a1.x,a1.y,a1.z,a1.w};             \
    const float wv[4] = {w4.x,w4.y,w4.z,w4.w};                                 \
    _Pragma("unroll") for (int r = 0; r < 8; ++r)                              \
      _Pragma("unroll") for (int c = 0; c < 4; ++c)                            \
        ACC[r][c] += av[r]*wv[c];                                              \
  }                                                                            \
} while (0)

__device__ __forceinline__ float sigmoidf_(float x) {
  return 1.f / (1.f + __expf(-x));
}

// ---------------- time embedding pipeline -> tproj[L][B][D] ----------------
__global__ __launch_bounds__(128) void k_time(
    const float* __restrict__ t,
    const float* __restrict__ te1_W, const float* __restrict__ te1_b,
    const float* __restrict__ te2_W, const float* __restrict__ te2_b,
    const float* __restrict__ tl_W,  const float* __restrict__ tl_b,
    float* __restrict__ tproj) {
  __shared__ float temb[128], h1[64], rt[64];
  int tid = threadIdx.x;
  for (int b = 0; b < BB; ++b) {
    float tv = t[b];
    {
      int j = tid & 63;
      float f = expf(-LOG1E4 * (float)j / 64.f);
      float a = tv * f;
      temb[tid] = (tid < 64) ? cosf(a) : sinf(a);
    }
    __syncthreads();
    if (tid < 64) {
      float acc = te1_b[tid];
      for (int k = 0; k < 128; ++k) acc += temb[k] * te1_W[k*64 + tid];
      h1[tid] = fmaxf(acc, 0.f);
    }
    __syncthreads();
    if (tid < 64) {
      float acc = te2_b[tid];
      for (int k = 0; k < 64; ++k) acc += h1[k] * te2_W[k*64 + tid];
      rt[tid] = fmaxf(acc, 0.f);   // relu(te)
    }
    __syncthreads();
    for (int i = 0; i < LL; ++i) {
      float acc = tl_b[i*128 + tid];
      for (int k = 0; k < 64; ++k) acc += rt[k] * tl_W[(i*64 + k)*128 + tid];
      tproj[(i*BB + b)*128 + tid] = acc;
    }
    __syncthreads();
  }
}

// ---------------- node pos-embed + node_W GEMM -> x (512 x 128) ----------------
__global__ __launch_bounds__(256) void k_node_embed(
    const float* __restrict__ coords, const float* __restrict__ W,
    const float* __restrict__ bias, float* __restrict__ x_out) {
  __shared__ float at[128*LDS_STR];
  int tid = threadIdx.x;
  int row = tid >> 2, part = tid & 3;
  int R = blockIdx.x*64 + row;
  float cy = coords[R*2 + 0], cx = coords[R*2 + 1];
#pragma unroll
  for (int q = 0; q < 32; ++q) {
    int c = part*32 + q;
    int k = (c < 64) ? c : c - 64;
    float v = (c < 64) ? cy : cx;
    int m = k >> 1;
    float inv = expf(-LOG1E4 * (float)m / 32.f);   // 10000^(-m/32), npf=64
    float a = v * TWO_PI * inv;
    at[c*LDS_STR + row] = (k & 1) ? cosf(a) : sinf(a);
  }
  __syncthreads();
  int tx = tid & 31, ty = tid >> 5;
  float acc[8][4] = {};
  TILE_GEMM(at, W, acc);
  float4 bb4 = *reinterpret_cast<const float4*>(bias + tx*4);
#pragma unroll
  for (int r = 0; r < 8; ++r) {
    int R2 = blockIdx.x*64 + ty*8 + r;
    float4 o = {acc[r][0]+bb4.x, acc[r][1]+bb4.y, acc[r][2]+bb4.z, acc[r][3]+bb4.w};
    *reinterpret_cast<float4*>(x_out + (size_t)R2*128 + tx*4) = o;
  }
}

// ---------------- edge pos-embed + edge_W GEMM -> e (131072 x 128) ----------------
__global__ __launch_bounds__(256) void k_edge_embed(
    const float* __restrict__ adj, const float* __restrict__ W,
    const float* __restrict__ bias, float* __restrict__ e_out) {
  __shared__ float at[128*LDS_STR];
  int tid = threadIdx.x;
  int row = tid >> 2, part = tid & 3;
  size_t R = (size_t)blockIdx.x*64 + row;
  float v = adj[R];
#pragma unroll
  for (int q = 0; q < 32; ++q) {
    int k = part*32 + q;
    int m = k >> 1;
    float inv = expf(-LOG1E4 * (float)m / 64.f);   // 10000^(-m/64), npf=128
    float a = v * inv;
    at[k*LDS_STR + row] = (k & 1) ? cosf(a) : sinf(a);
  }
  __syncthreads();
  int tx = tid & 31, ty = tid >> 5;
  float acc[8][4] = {};
  TILE_GEMM(at, W, acc);
  float4 bb4 = *reinterpret_cast<const float4*>(bias + tx*4);
#pragma unroll
  for (int r = 0; r < 8; ++r) {
    size_t R2 = (size_t)blockIdx.x*64 + ty*8 + r;
    float4 o = {acc[r][0]+bb4.x, acc[r][1]+bb4.y, acc[r][2]+bb4.z, acc[r][3]+bb4.w};
    *reinterpret_cast<float4*>(e_out + R2*128 + tx*4) = o;
  }
}

// ---------------- per-layer node linears: Uh,Vh,Ax,Bx (512 rows) ----------------
__global__ __launch_bounds__(128) void k_node4(
    const float* __restrict__ x,
    const float* __restrict__ UW, const float* __restrict__ Ub,
    const float* __restrict__ VW, const float* __restrict__ Vb,
    const float* __restrict__ AW, const float* __restrict__ Ab,
    const float* __restrict__ BW, const float* __restrict__ Bb,
    float* __restrict__ Uh, float* __restrict__ Vh,
    float* __restrict__ Axo, float* __restrict__ Bxo) {
  __shared__ float xr[128];
  int R = blockIdx.x, d = threadIdx.x;
  xr[d] = x[(size_t)R*128 + d];
  __syncthreads();
  float au = Ub[d], av = Vb[d], aa = Ab[d], ab = Bb[d];
  for (int k = 0; k < 128; ++k) {
    float xv = xr[k];
    au += xv * UW[k*128 + d];
    av += xv * VW[k*128 + d];
    aa += xv * AW[k*128 + d];
    ab += xv * BW[k*128 + d];
  }
  Uh[(size_t)R*128 + d] = au;
  Vh[(size_t)R*128 + d] = av;
  Axo[(size_t)R*128 + d] = aa;
  Bxo[(size_t)R*128 + d] = ab;
}

// ================= fused per-layer kernel ====================
// One block per (b,i). 4 j-tiles of 64 edge rows each:
//   GEMM1: gate = e@C_W + Cb + Ax[i] + Bx[j]   (never materialized)
//   agg  += sigmoid(gate) * Vh[j]              (register accumulation)
//   sv    = silu(ln2(relu(ln1(gate)) + tproj)) (in-register, row LN via shfl)
//   GEMM2: e = e_in + sv @ plo_W + plo_b
// Epilogue: x[i] += relu(ln(Uh[i] + agg));  last layer also accumulates GN stats.
__global__ __launch_bounds__(256) void k_layer(
    float* __restrict__ e,
    const float* __restrict__ CW, const float* __restrict__ Cb,
    const float* __restrict__ Ax, const float* __restrict__ Bx,
    const float* __restrict__ Vh, const float* __restrict__ Uh,
    const float* __restrict__ lnh_s, const float* __restrict__ lnh_b,
    const float* __restrict__ lne_s, const float* __restrict__ lne_b,
    const float* __restrict__ tproj_i,
    const float* __restrict__ plo_s, const float* __restrict__ plo_bln,
    const float* __restrict__ ploW, const float* __restrict__ plob,
    float* __restrict__ x, float* __restrict__ stats_raw, int do_stats) {
  __shared__ float at[128*LDS_STR];   // ~34.8 KB
  __shared__ float aggL[128];
  __shared__ float sgrp[64];
  __shared__ float redw[8];

  const int tid = threadIdx.x;
  const int bi = blockIdx.x;          // b*256 + i
  const int b  = bi >> 8;
  const int row = tid >> 2, part = tid & 3;
  const int tx = tid & 31, ty = tid >> 5;

  // per-column (d = tx*4..tx*4+3) constants
  const float4 cb4  = *reinterpret_cast<const float4*>(Cb + tx*4);
  const float4 ax4  = *reinterpret_cast<const float4*>(Ax + (size_t)bi*128 + tx*4);
  const float4 lnes = *reinterpret_cast<const float4*>(lne_s + tx*4);
  const float4 lneb = *reinterpret_cast<const float4*>(lne_b + tx*4);
  const float4 tp4  = *reinterpret_cast<const float4*>(tproj_i + b*128 + tx*4);
  const float4 plos = *reinterpret_cast<const float4*>(plo_s + tx*4);
  const float4 plobl= *reinterpret_cast<const float4*>(plo_bln + tx*4);
  const float4 pb4  = *reinterpret_cast<const float4*>(plob + tx*4);

  float pvec[4] = {0.f, 0.f, 0.f, 0.f};   // agg partials (cols tx*4..+3)
  float gs = 0.f, gs2 = 0.f;              // GN-stats partials (group = tx)

  for (int jt = 0; jt < 4; ++jt) {
    const size_t rbase = (size_t)bi*256 + jt*64;   // global edge row base
    __syncthreads();   // protect at[] from previous iteration's readers
    // ---- stage e tile (64 rows x 128 cols), transposed into LDS ----
    {
      const float4* erow = reinterpret_cast<const float4*>(e + (rbase + row)*128 + part*32);
#pragma unroll
      for (int q = 0; q < 8; ++q) {
        float4 f = erow[q];
        int k = part*32 + q*4;
        at[(k+0)*LDS_STR + row] = f.x;
        at[(k+1)*LDS_STR + row] = f.y;
        at[(k+2)*LDS_STR + row] = f.z;
        at[(k+3)*LDS_STR + row] = f.w;
      }
    }
    __syncthreads();
    // ---- GEMM1: gate = e @ C_W ----
    float acc[8][4] = {};
    TILE_GEMM(at, CW, acc);
    // ---- biases + per-row elementwise pipeline ----
#pragma unroll
    for (int r = 0; r < 8; ++r) {
      const size_t j = (size_t)jt*64 + ty*8 + r;
      const float4 bx4 = *reinterpret_cast<const float4*>(Bx + ((size_t)b*256 + j)*128 + tx*4);
      float g0 = acc[r][0] + cb4.x + ax4.x + bx4.x;
      float g1 = acc[r][1] + cb4.y + ax4.y + bx4.y;
      float g2 = acc[r][2] + cb4.z + ax4.z + bx4.z;
      float g3 = acc[r][3] + cb4.w + ax4.w + bx4.w;
      // LN1 row stats over 128 cols (32 lanes x 4 each, same half-wave)
      float p1 = g0+g1+g2+g3;
      float p2 = g0*g0+g1*g1+g2*g2+g3*g3;
#pragma unroll
      for (int m = 1; m <= 16; m <<= 1) { p1 += __shfl_xor(p1, m); p2 += __shfl_xor(p2, m); }
      const float mean = p1 * (1.f/128.f);
      const float rs = rsqrtf(p2 * (1.f/128.f) - mean*mean + 1e-5f);
      // aggregation: sigmoid(gate) * Vh[j]
      const float4 vh = *reinterpret_cast<const float4*>(Vh + ((size_t)b*256 + j)*128 + tx*4);
      pvec[0] += vh.x * sigmoidf_(g0);
      pvec[1] += vh.y * sigmoidf_(g1);
      pvec[2] += vh.z * sigmoidf_(g2);
      pvec[3] += vh.w * sigmoidf_(g3);
      // relu(LN1) + tproj
      float t0 = fmaxf((g0-mean)*rs*lnes.x + lneb.x, 0.f) + tp4.x;
      float t1 = fmaxf((g1-mean)*rs*lnes.y + lneb.y, 0.f) + tp4.y;
      float t2 = fmaxf((g2-mean)*rs*lnes.z + lneb.z, 0.f) + tp4.z;
      float t3 = fmaxf((g3-mean)*rs*lnes.w + lneb.w, 0.f) + tp4.w;
      // LN2 row stats
      float p3 = t0+t1+t2+t3;
      float p4 = t0*t0+t1*t1+t2*t2+t3*t3;
#pragma unroll
      for (int m = 1; m <= 16; m <<= 1) { p3 += __shfl_xor(p3, m); p4 += __shfl_xor(p4, m); }
      const float mean2 = p3 * (1.f/128.f);
      const float rs2 = rsqrtf(p4 * (1.f/128.f) - mean2*mean2 + 1e-5f);
      // silu(LN2) -> store back into acc as GEMM2 A-values
      float s0 = (t0-mean2)*rs2*plos.x + plobl.x;
      float s1 = (t1-mean2)*rs2*plos.y + plobl.y;
      float s2 = (t2-mean2)*rs2*plos.z + plobl.z;
      float s3 = (t3-mean2)*rs2*plos.w + plobl.w;
      acc[r][0] = s0 * sigmoidf_(s0);
      acc[r][1] = s1 * sigmoidf_(s1);
      acc[r][2] = s2 * sigmoidf_(s2);
      acc[r][3] = s3 * sigmoidf_(s3);
    }
    __syncthreads();   // all GEMM1 LDS reads complete before overwriting at[]
    // ---- stage silu values (transposed) for GEMM2 ----
#pragma unroll
    for (int r = 0; r < 8; ++r)
#pragma unroll
      for (int c = 0; c < 4; ++c)
        at[(tx*4+c)*LDS_STR + (ty*8+r)] = acc[r][c];
    __syncthreads();
    // ---- GEMM2: e = e_in + sv @ plo_W + plo_b ----
    float acc2[8][4];
#pragma unroll
    for (int r = 0; r < 8; ++r) {
      const float4 ein = *reinterpret_cast<const float4*>(e + (rbase + ty*8 + r)*128 + tx*4);
      acc2[r][0] = ein.x + pb4.x;
      acc2[r][1] = ein.y + pb4.y;
      acc2[r][2] = ein.z + pb4.z;
      acc2[r][3] = ein.w + pb4.w;
    }
    TILE_GEMM(at, ploW, acc2);
#pragma unroll
    for (int r = 0; r < 8; ++r) {
      float4 o = {acc2[r][0], acc2[r][1], acc2[r][2], acc2[r][3]};
      *reinterpret_cast<float4*>(e + (rbase + ty*8 + r)*128 + tx*4) = o;
      if (do_stats) {
        gs  += o.x + o.y + o.z + o.w;
        gs2 += o.x*o.x + o.y*o.y + o.z*o.z + o.w*o.w;
      }
    }
  }

  // ---- epilogue: agg reduce -> h_new -> x update; GN stats atomics ----
  __syncthreads();
  if (tid < 128) aggL[tid] = 0.f;
  if (tid < 64)  sgrp[tid] = 0.f;
  __syncthreads();
#pragma unroll
  for (int c = 0; c < 4; ++c) {
    float v = pvec[c] + __shfl_xor(pvec[c], 32);
    if ((tid & 63) < 32) atomicAdd(&aggL[tx*4 + c], v);
  }
  if (do_stats) {
    float a  = gs  + __shfl_xor(gs, 32);
    float a2 = gs2 + __shfl_xor(gs2, 32);
    if ((tid & 63) < 32) { atomicAdd(&sgrp[tx*2], a); atomicAdd(&sgrp[tx*2+1], a2); }
  }
  __syncthreads();
  float u = 0.f;
  if (tid < 128) u = Uh[(size_t)bi*128 + tid] + aggL[tid];
  float s = u, s2 = u*u;
#pragma unroll
  for (int m = 1; m <= 32; m <<= 1) { s += __shfl_xor(s, m); s2 += __shfl_xor(s2, m); }
  if ((tid & 63) == 0 && tid < 128) { redw[tid>>6] = s; redw[2 + (tid>>6)] = s2; }
  __syncthreads();
  if (tid < 128) {
    const float S = redw[0] + redw[1], S2 = redw[2] + redw[3];
    const float mean = S * (1.f/128.f);
    const float rs = rsqrtf(S2 * (1.f/128.f) - mean*mean + 1e-5f);
    const float h = fmaxf((u - mean)*rs*lnh_s[tid] + lnh_b[tid], 0.f);
    x[(size_t)bi*128 + tid] += h;
  }
  if (do_stats && tid < 32) {
    atomicAdd(&stats_raw[((size_t)b*32 + tid)*2],     sgrp[tid*2]);
    atomicAdd(&stats_raw[((size_t)b*32 + tid)*2 + 1], sgrp[tid*2+1]);
  }
}

// ---------------- zero the GN stats accumulators ----------------
__global__ __launch_bounds__(128) void k_zero(float* __restrict__ p) {
  p[threadIdx.x] = 0.f;
}

// ---------------- finalize GN stats: sums -> mean/rs ----------------
__global__ __launch_bounds__(64) void k_gnfin(
    const float* __restrict__ raw, float* __restrict__ stats) {
  int i = threadIdx.x;           // b*32+g over 64
  const float cnt = (float)(NN*NN*4);
  float S  = raw[i*2];
  float S2 = raw[i*2 + 1];
  float mean = S / cnt;
  float var = S2 / cnt - mean*mean;
  stats[i*2]     = mean;
  stats[i*2 + 1] = rsqrtf(var + 1e-5f);
}

// ---------------- final: out = relu(gn(e)) . conv_W + conv_b ----------------
__global__ __launch_bounds__(256) void k_out(
    const float* __restrict__ e, const float* __restrict__ stats,
    const float* __restrict__ gn_s, const float* __restrict__ gn_b,
    const float* __restrict__ convW, const float* __restrict__ convb,
    float* __restrict__ out) {
  int tid = threadIdx.x;
  int row = tid >> 2, part = tid & 3;
  size_t R = (size_t)blockIdx.x*64 + row;
  size_t b = R >> 16;
  float acc = 0.f;
  const float4* er = reinterpret_cast<const float4*>(e + R*128 + part*32);
#pragma unroll
  for (int q = 0; q < 8; ++q) {
    float4 f = er[q];
    float fv[4] = {f.x, f.y, f.z, f.w};
#pragma unroll
    for (int l = 0; l < 4; ++l) {
      int c = part*32 + q*4 + l;
      int g = c >> 2;
      float mean = stats[(b*NGROUP + g)*2 + 0];
      float rs   = stats[(b*NGROUP + g)*2 + 1];
      float t = (fv[l] - mean)*rs*gn_s[c] + gn_b[c];
      acc += fmaxf(t, 0.f) * convW[c];
    }
  }
  acc += __shfl_xor(acc, 1);
  acc += __shfl_xor(acc, 2);
  if (part == 0) out[R] = acc + convb[0];
}

extern "C" void kernel_launch(void* const* d_in, const int* in_sizes, int n_in,
                              void* d_out, int out_size, void* d_ws, size_t ws_size,
                              hipStream_t stream) {
  const float* coords  = (const float*)d_in[0];
  const float* adj_t   = (const float*)d_in[1];
  const float* t       = (const float*)d_in[2];
  const float* node_W  = (const float*)d_in[3];
  const float* node_b  = (const float*)d_in[4];
  const float* edge_W  = (const float*)d_in[5];
  const float* edge_b  = (const float*)d_in[6];
  const float* te1_W   = (const float*)d_in[7];
  const float* te1_b   = (const float*)d_in[8];
  const float* te2_W   = (const float*)d_in[9];
  const float* te2_b   = (const float*)d_in[10];
  const float* A_W     = (const float*)d_in[11];
  const float* A_b     = (const float*)d_in[12];
  const float* B_W     = (const float*)d_in[13];
  const float* B_b     = (const float*)d_in[14];
  const float* C_W     = (const float*)d_in[15];
  const float* C_b     = (const float*)d_in[16];
  const float* U_W     = (const float*)d_in[17];
  const float* U_b     = (const float*)d_in[18];
  const float* V_W     = (const float*)d_in[19];
  const float* V_b     = (const float*)d_in[20];
  const float* lnh_s   = (const float*)d_in[21];
  const float* lnh_b   = (const float*)d_in[22];
  const float* lne_s   = (const float*)d_in[23];
  const float* lne_b   = (const float*)d_in[24];
  const float* tl_W    = (const float*)d_in[25];
  const float* tl_b    = (const float*)d_in[26];
  const float* plo_ln_s= (const float*)d_in[27];
  const float* plo_ln_b= (const float*)d_in[28];
  const float* plo_W   = (const float*)d_in[29];
  const float* plo_b   = (const float*)d_in[30];
  const float* gn_s    = (const float*)d_in[31];
  const float* gn_b    = (const float*)d_in[32];
  const float* conv_W  = (const float*)d_in[33];
  const float* conv_b  = (const float*)d_in[34];

  float* ws   = (float*)d_ws;
  float* e     = ws;                        // 16777216 floats
  float* x     = e + (size_t)NROWS*128;     // 65536
  float* Uh    = x + 65536;
  float* Vh    = Uh + 65536;
  float* Ax    = Vh + 65536;
  float* Bx    = Ax + 65536;
  float* tproj = Bx + 65536;                // L*B*128 = 1024
  float* sraw  = tproj + 1024;              // B*32*2 = 128
  float* stats = sraw + 128;                // B*32*2 = 128

  k_zero<<<1, 128, 0, stream>>>(sraw);
  k_time<<<1, 128, 0, stream>>>(t, te1_W, te1_b, te2_W, te2_b, tl_W, tl_b, tproj);
  k_node_embed<<<8, 256, 0, stream>>>(coords, node_W, node_b, x);
  k_edge_embed<<<NROWS/64, 256, 0, stream>>>(adj_t, edge_W, edge_b, e);

  for (int i = 0; i < LL; ++i) {
    k_node4<<<BB*NN, 128, 0, stream>>>(x,
        U_W + (size_t)i*16384, U_b + i*128,
        V_W + (size_t)i*16384, V_b + i*128,
        A_W + (size_t)i*16384, A_b + i*128,
        B_W + (size_t)i*16384, B_b + i*128,
        Uh, Vh, Ax, Bx);
    k_layer<<<BB*NN, 256, 0, stream>>>(e,
        C_W + (size_t)i*16384, C_b + i*128,
        Ax, Bx, Vh, Uh,
        lnh_s + i*128, lnh_b + i*128,
        lne_s + i*128, lne_b + i*128,
        tproj + i*BB*128,
        plo_ln_s + i*128, plo_ln_b + i*128,
        plo_W + (size_t)i*16384, plo_b + i*128,
        x, sraw, (i == LL-1) ? 1 : 0);
  }

  k_gnfin<<<1, 64, 0, stream>>>(sraw, stats);
  k_out<<<NROWS/64, 256, 0, stream>>>(e, stats, gn_s, gn_b, conv_W, conv_b,
                                      (float*)d_out);
}

// Round 3
// 775.189 us; speedup vs baseline: 1.4836x; 1.4836x over previous
//
#include <hip/hip_runtime.h>
#include <hip/hip_bf16.h>

typedef unsigned short u16;
typedef __attribute__((ext_vector_type(8))) short short8;
typedef __attribute__((ext_vector_type(8))) unsigned short ushort8;
typedef __attribute__((ext_vector_type(4))) float f32x4;

#define BB 2
#define NN 256
#define DD 128
#define TDD 64
#define LL 4
#define NGROUP 32
#define NROWS (BB*NN*NN)      // 131072 edge rows
#define LDS_STR 68            // padded LDS stride for fp32 embed kernels

#define LOG1E4 9.210340371976184f
#define TWO_PI 6.283185307179586f

// ---------------- fp32 tile GEMM (embed kernels only) ----------------
#define TILE_GEMM(AT, WPTR, ACC) do {                                          \
  _Pragma("unroll 4")                                                          \
  for (int k = 0; k < 128; ++k) {                                              \
    const float4 w4 = *reinterpret_cast<const float4*>((WPTR) + k*128 + tx*4); \
    const float4 a0 = *reinterpret_cast<const float4*>(&(AT)[k*LDS_STR + ty*8]);     \
    const float4 a1 = *reinterpret_cast<const float4*>(&(AT)[k*LDS_STR + ty*8 + 4]); \
    const float av[8] = {a0.x,a0.y,a0.z,a0.w,a1.x,a1.y,a1.z,a1.w};             \
    const float wv[4] = {w4.x,w4.y,w4.z,w4.w};                                 \
    _Pragma("unroll") for (int r = 0; r < 8; ++r)                              \
      _Pragma("unroll") for (int c = 0; c < 4; ++c)                            \
        ACC[r][c] += av[r]*wv[c];                                              \
  }                                                                            \
} while (0)

__device__ __forceinline__ float sigmoidf_(float x) {
  return 1.f / (1.f + __expf(-x));
}

// round-to-nearest-even f32 -> bf16 bits
__device__ __forceinline__ u16 f2bf(float f) {
  union { float f; unsigned int u; } c; c.f = f;
  unsigned int r = (c.u + 0x7FFFu + ((c.u >> 16) & 1u)) >> 16;
  return (u16)r;
}

// ---------------- time embedding pipeline -> tproj[L][B][D] ----------------
__global__ __launch_bounds__(128) void k_time(
    const float* __restrict__ t,
    const float* __restrict__ te1_W, const float* __restrict__ te1_b,
    const float* __restrict__ te2_W, const float* __restrict__ te2_b,
    const float* __restrict__ tl_W,  const float* __restrict__ tl_b,
    float* __restrict__ tproj) {
  __shared__ float temb[128], h1[64], rt[64];
  int tid = threadIdx.x;
  for (int b = 0; b < BB; ++b) {
    float tv = t[b];
    {
      int j = tid & 63;
      float f = expf(-LOG1E4 * (float)j / 64.f);
      float a = tv * f;
      temb[tid] = (tid < 64) ? cosf(a) : sinf(a);
    }
    __syncthreads();
    if (tid < 64) {
      float acc = te1_b[tid];
      for (int k = 0; k < 128; ++k) acc += temb[k] * te1_W[k*64 + tid];
      h1[tid] = fmaxf(acc, 0.f);
    }
    __syncthreads();
    if (tid < 64) {
      float acc = te2_b[tid];
      for (int k = 0; k < 64; ++k) acc += h1[k] * te2_W[k*64 + tid];
      rt[tid] = fmaxf(acc, 0.f);   // relu(te)
    }
    __syncthreads();
    for (int i = 0; i < LL; ++i) {
      float acc = tl_b[i*128 + tid];
      for (int k = 0; k < 64; ++k) acc += rt[k] * tl_W[(i*64 + k)*128 + tid];
      tproj[(i*BB + b)*128 + tid] = acc;
    }
    __syncthreads();
  }
}

// ---------------- node pos-embed + node_W GEMM -> x (512 x 128) ----------------
__global__ __launch_bounds__(256) void k_node_embed(
    const float* __restrict__ coords, const float* __restrict__ W,
    const float* __restrict__ bias, float* __restrict__ x_out) {
  __shared__ float at[128*LDS_STR];
  int tid = threadIdx.x;
  int row = tid >> 2, part = tid & 3;
  int R = blockIdx.x*64 + row;
  float cy = coords[R*2 + 0], cx = coords[R*2 + 1];
#pragma unroll
  for (int q = 0; q < 32; ++q) {
    int c = part*32 + q;
    int k = (c < 64) ? c : c - 64;
    float v = (c < 64) ? cy : cx;
    int m = k >> 1;
    float inv = expf(-LOG1E4 * (float)m / 32.f);
    float a = v * TWO_PI * inv;
    at[c*LDS_STR + row] = (k & 1) ? cosf(a) : sinf(a);
  }
  __syncthreads();
  int tx = tid & 31, ty = tid >> 5;
  float acc[8][4] = {};
  TILE_GEMM(at, W, acc);
  float4 bb4 = *reinterpret_cast<const float4*>(bias + tx*4);
#pragma unroll
  for (int r = 0; r < 8; ++r) {
    int R2 = blockIdx.x*64 + ty*8 + r;
    float4 o = {acc[r][0]+bb4.x, acc[r][1]+bb4.y, acc[r][2]+bb4.z, acc[r][3]+bb4.w};
    *reinterpret_cast<float4*>(x_out + (size_t)R2*128 + tx*4) = o;
  }
}

// ---------------- edge pos-embed + edge_W GEMM -> e (131072 x 128) ----------------
__global__ __launch_bounds__(256) void k_edge_embed(
    const float* __restrict__ adj, const float* __restrict__ W,
    const float* __restrict__ bias, float* __restrict__ e_out) {
  __shared__ float at[128*LDS_STR];
  int tid = threadIdx.x;
  int row = tid >> 2, part = tid & 3;
  size_t R = (size_t)blockIdx.x*64 + row;
  float v = adj[R];
#pragma unroll
  for (int q = 0; q < 32; ++q) {
    int k = part*32 + q;
    int m = k >> 1;
    float inv = expf(-LOG1E4 * (float)m / 64.f);
    float a = v * inv;
    at[k*LDS_STR + row] = (k & 1) ? cosf(a) : sinf(a);
  }
  __syncthreads();
  int tx = tid & 31, ty = tid >> 5;
  float acc[8][4] = {};
  TILE_GEMM(at, W, acc);
  float4 bb4 = *reinterpret_cast<const float4*>(bias + tx*4);
#pragma unroll
  for (int r = 0; r < 8; ++r) {
    size_t R2 = (size_t)blockIdx.x*64 + ty*8 + r;
    float4 o = {acc[r][0]+bb4.x, acc[r][1]+bb4.y, acc[r][2]+bb4.z, acc[r][3]+bb4.w};
    *reinterpret_cast<float4*>(e_out + R2*128 + tx*4) = o;
  }
}

// ---------------- per-layer node linears: Uh,Vh,Ax,Bx (512 rows) ----------------
__global__ __launch_bounds__(128) void k_node4(
    const float* __restrict__ x,
    const float* __restrict__ UW, const float* __restrict__ Ub,
    const float* __restrict__ VW, const float* __restrict__ Vb,
    const float* __restrict__ AW, const float* __restrict__ Ab,
    const float* __restrict__ BW, const float* __restrict__ Bb,
    float* __restrict__ Uh, float* __restrict__ Vh,
    float* __restrict__ Axo, float* __restrict__ Bxo) {
  __shared__ float xr[128];
  int R = blockIdx.x, d = threadIdx.x;
  xr[d] = x[(size_t)R*128 + d];
  __syncthreads();
  float au = Ub[d], av = Vb[d], aa = Ab[d], ab = Bb[d];
  for (int k = 0; k < 128; ++k) {
    float xv = xr[k];
    au += xv * UW[k*128 + d];
    av += xv * VW[k*128 + d];
    aa += xv * AW[k*128 + d];
    ab += xv * BW[k*128 + d];
  }
  Uh[(size_t)R*128 + d] = au;
  Vh[(size_t)R*128 + d] = av;
  Axo[(size_t)R*128 + d] = aa;
  Bxo[(size_t)R*128 + d] = ab;
}

// ---------------- weight prep: bf16 transposed copies WT[n][k] ----------------
__global__ __launch_bounds__(256) void k_wprep(
    const float* __restrict__ CW, const float* __restrict__ PW,
    u16* __restrict__ WTC, u16* __restrict__ WTP) {
  int idx = blockIdx.x*256 + threadIdx.x;    // 0..131071
  int m = idx >> 14;                          // 0..7 (layer*2 + type)
  int r = idx & 16383;
  int layer = m >> 1;
  int n = r >> 7, k = r & 127;
  if ((m & 1) == 0)
    WTC[layer*16384 + n*128 + k] = f2bf(CW[(size_t)layer*16384 + k*128 + n]);
  else
    WTP[layer*16384 + n*128 + k] = f2bf(PW[(size_t)layer*16384 + k*128 + n]);
}

// ================= fused per-layer MFMA kernel ====================
// grid = 2048: block = (bi, jt) handles 64 edge rows (j-tile) of node (b,i).
// 4 waves; wave w owns output cols [w*32, w*32+32).
__global__ __launch_bounds__(256) void k_layer(
    float* __restrict__ e,
    const u16* __restrict__ WTC, const u16* __restrict__ WTP,
    const float* __restrict__ Cb, const float* __restrict__ Ax,
    const float* __restrict__ Bx, const float* __restrict__ Vh,
    const float* __restrict__ lnes_g, const float* __restrict__ lneb_g,
    const float* __restrict__ tp_g,
    const float* __restrict__ plos_g, const float* __restrict__ plobl_g,
    const float* __restrict__ plob_g,
    float* __restrict__ aggP, float* __restrict__ sraw, int do_stats) {

  __shared__ __align__(16) u16  Abuf[64*128];   // 16 KB bf16 swizzled (e, then sv)
  __shared__ __align__(16) float vh[64*128];    // 32 KB f32 swizzled
  __shared__ __align__(16) float lnbuf[64*16];  // 4 KB row-permuted LN partials

  const int tid = threadIdx.x;
  const int blk = blockIdx.x;
  const int bi = blk >> 2;
  const int b  = bi >> 8;
  const int jt = blk & 3;
  const int jbase = jt * 64;
  const size_t rbase = (size_t)bi*256 + jbase;

  // ---- stage e (bf16, chunk^(row&7) swizzle) and Vh (f32, (row>>2)&7 swizzle) ----
  {
    const int row = tid >> 2, part = tid & 3;
    const float* esrc = e + (rbase + row)*128 + part*32;
    u16* arow = Abuf + row*128;
    const int rs7 = row & 7;
#pragma unroll
    for (int c = 0; c < 4; ++c) {
      float4 u = *reinterpret_cast<const float4*>(esrc + c*8);
      float4 v = *reinterpret_cast<const float4*>(esrc + c*8 + 4);
      int sl = (part*4 + c) ^ rs7;
      ushort8 h = {f2bf(u.x),f2bf(u.y),f2bf(u.z),f2bf(u.w),
                   f2bf(v.x),f2bf(v.y),f2bf(v.z),f2bf(v.w)};
      *reinterpret_cast<ushort8*>(arow + sl*8) = h;
    }
    const float* vsrc = Vh + ((size_t)b*256 + jbase + row)*128 + part*32;
    float* vrow = vh + row*128;
    const int vsw = (row >> 2) & 7;
#pragma unroll
    for (int q = 0; q < 8; ++q) {
      float4 f = *reinterpret_cast<const float4*>(vsrc + q*4);
      int cc = (part*8 + q) ^ vsw;
      *reinterpret_cast<float4*>(vrow + cc*4) = f;
    }
  }
  __syncthreads();

  const int l  = tid & 63;
  const int w  = tid >> 6;
  const int lg = l >> 4;          // k-group / row-group
  const int ln = l & 15;
  const int col0 = w*32 + ln;     // wave's first owned col for this lane

  // per-col constants (cols col0, col0+16)
  float cb[2], ax[2], tp[2], lsc[2], lbi[2], psc[2], pbi[2], pb[2];
#pragma unroll
  for (int q = 0; q < 2; ++q) {
    int c = col0 + q*16;
    cb[q]  = Cb[c];
    ax[q]  = Ax[(size_t)bi*128 + c];
    tp[q]  = tp_g[b*128 + c];
    lsc[q] = lnes_g[c];  lbi[q] = lneb_g[c];
    psc[q] = plos_g[c];  pbi[q] = plobl_g[c];
    pb[q]  = plob_g[c];
  }

  // ---- B1 fragments (C_W^T bf16), cached in VGPRs ----
  short8 bf[2][4];
#pragma unroll
  for (int ntl = 0; ntl < 2; ++ntl)
#pragma unroll
    for (int ks = 0; ks < 4; ++ks)
      bf[ntl][ks] = *reinterpret_cast<const short8*>(
          WTC + ((w*2 + ntl)*16 + ln)*128 + ks*32 + lg*8);

  // ---- GEMM1: gate = e @ C_W ----
  f32x4 acc[4][2];
#pragma unroll
  for (int mt = 0; mt < 4; ++mt) { acc[mt][0] = (f32x4)(0.f); acc[mt][1] = (f32x4)(0.f); }
#pragma unroll
  for (int mt = 0; mt < 4; ++mt) {
    const u16* ar = Abuf + (mt*16 + ln)*128;
    const int rs7 = ln & 7;
#pragma unroll
    for (int ks = 0; ks < 4; ++ks) {
      short8 a = *reinterpret_cast<const short8*>(ar + (((ks*4 + lg) ^ rs7) << 3));
      acc[mt][0] = __builtin_amdgcn_mfma_f32_16x16x32_bf16(a, bf[0][ks], acc[mt][0], 0, 0, 0);
      acc[mt][1] = __builtin_amdgcn_mfma_f32_16x16x32_bf16(a, bf[1][ks], acc[mt][1], 0, 0, 0);
    }
  }

  // ---- phase A: gate biases, agg accumulation, LN1 partials ----
  float av0 = 0.f, av1 = 0.f;
#pragma unroll
  for (int mt = 0; mt < 4; ++mt) {
#pragma unroll
    for (int rg = 0; rg < 4; ++rg) {
      int row = mt*16 + lg*4 + rg;
      size_t brow = ((size_t)b*256 + jbase + row)*128;
      float g0 = acc[mt][0][rg] + cb[0] + ax[0] + Bx[brow + col0];
      float g1 = acc[mt][1][rg] + cb[1] + ax[1] + Bx[brow + col0 + 16];
      acc[mt][0][rg] = g0;  acc[mt][1][rg] = g1;
      float s = g0 + g1, s2 = g0*g0 + g1*g1;
      s += __shfl_xor(s, 1);  s2 += __shfl_xor(s2, 1);
      s += __shfl_xor(s, 2);  s2 += __shfl_xor(s2, 2);
      s += __shfl_xor(s, 4);  s2 += __shfl_xor(s2, 4);
      s += __shfl_xor(s, 8);  s2 += __shfl_xor(s2, 8);
      if (ln == 0) {
        int lr = (row >> 2) | ((row & 3) << 4);
        lnbuf[lr*16 + w]     = s;
        lnbuf[lr*16 + 4 + w] = s2;
      }
      int swz = ((row >> 2) & 7) << 2;
      av0 += vh[row*128 + (col0 ^ swz)]        * sigmoidf_(g0);
      av1 += vh[row*128 + ((col0 + 16) ^ swz)] * sigmoidf_(g1);
    }
  }
  __syncthreads();

  // ---- phase B: LN1 apply + relu + tproj, LN2 partials ----
#pragma unroll
  for (int mt = 0; mt < 4; ++mt) {
#pragma unroll
    for (int rg = 0; rg < 4; ++rg) {
      int row = mt*16 + lg*4 + rg;
      int lr = (row >> 2) | ((row & 3) << 4);
      f32x4 sq = *reinterpret_cast<f32x4*>(&lnbuf[lr*16]);
      f32x4 qq = *reinterpret_cast<f32x4*>(&lnbuf[lr*16 + 4]);
      float mean = (sq[0]+sq[1]+sq[2]+sq[3]) * (1.f/128.f);
      float m2   = (qq[0]+qq[1]+qq[2]+qq[3]) * (1.f/128.f);
      float rs = rsqrtf(m2 - mean*mean + 1e-5f);
      float t0 = fmaxf((acc[mt][0][rg]-mean)*rs*lsc[0] + lbi[0], 0.f) + tp[0];
      float t1 = fmaxf((acc[mt][1][rg]-mean)*rs*lsc[1] + lbi[1], 0.f) + tp[1];
      acc[mt][0][rg] = t0;  acc[mt][1][rg] = t1;
      float s = t0 + t1, s2 = t0*t0 + t1*t1;
      s += __shfl_xor(s, 1);  s2 += __shfl_xor(s2, 1);
      s += __shfl_xor(s, 2);  s2 += __shfl_xor(s2, 2);
      s += __shfl_xor(s, 4);  s2 += __shfl_xor(s2, 4);
      s += __shfl_xor(s, 8);  s2 += __shfl_xor(s2, 8);
      if (ln == 0) {
        lnbuf[lr*16 + 8 + w]  = s;
        lnbuf[lr*16 + 12 + w] = s2;
      }
    }
  }
  __syncthreads();

  // ---- phase C: LN2 apply + silu -> Abuf (bf16, swizzled) ----
#pragma unroll
  for (int mt = 0; mt < 4; ++mt) {
#pragma unroll
    for (int rg = 0; rg < 4; ++rg) {
      int row = mt*16 + lg*4 + rg;
      int lr = (row >> 2) | ((row & 3) << 4);
      f32x4 sq = *reinterpret_cast<f32x4*>(&lnbuf[lr*16 + 8]);
      f32x4 qq = *reinterpret_cast<f32x4*>(&lnbuf[lr*16 + 12]);
      float mean = (sq[0]+sq[1]+sq[2]+sq[3]) * (1.f/128.f);
      float m2   = (qq[0]+qq[1]+qq[2]+qq[3]) * (1.f/128.f);
      float rs = rsqrtf(m2 - mean*mean + 1e-5f);
      float v0 = (acc[mt][0][rg]-mean)*rs*psc[0] + pbi[0];
      float v1 = (acc[mt][1][rg]-mean)*rs*psc[1] + pbi[1];
      v0 = v0 * sigmoidf_(v0);
      v1 = v1 * sigmoidf_(v1);
      int rs7 = row & 7;
      int c0 = col0, c1 = col0 + 16;
      Abuf[row*128 + (((c0>>3) ^ rs7) << 3) + (c0 & 7)] = f2bf(v0);
      Abuf[row*128 + (((c1>>3) ^ rs7) << 3) + (c1 & 7)] = f2bf(v1);
    }
  }
  __syncthreads();

  // ---- GEMM2: e = e_in + sv @ plo_W + plo_b ----
#pragma unroll
  for (int ntl = 0; ntl < 2; ++ntl)
#pragma unroll
    for (int ks = 0; ks < 4; ++ks)
      bf[ntl][ks] = *reinterpret_cast<const short8*>(
          WTP + ((w*2 + ntl)*16 + ln)*128 + ks*32 + lg*8);

  f32x4 acc2[4][2];
#pragma unroll
  for (int mt = 0; mt < 4; ++mt) {
#pragma unroll
    for (int rg = 0; rg < 4; ++rg) {
      int row = mt*16 + lg*4 + rg;
      acc2[mt][0][rg] = e[(rbase + row)*128 + col0]      + pb[0];
      acc2[mt][1][rg] = e[(rbase + row)*128 + col0 + 16] + pb[1];
    }
  }
#pragma unroll
  for (int mt = 0; mt < 4; ++mt) {
    const u16* ar = Abuf + (mt*16 + ln)*128;
    const int rs7 = ln & 7;
#pragma unroll
    for (int ks = 0; ks < 4; ++ks) {
      short8 a = *reinterpret_cast<const short8*>(ar + (((ks*4 + lg) ^ rs7) << 3));
      acc2[mt][0] = __builtin_amdgcn_mfma_f32_16x16x32_bf16(a, bf[0][ks], acc2[mt][0], 0, 0, 0);
      acc2[mt][1] = __builtin_amdgcn_mfma_f32_16x16x32_bf16(a, bf[1][ks], acc2[mt][1], 0, 0, 0);
    }
  }

  float gsA = 0.f, gs2A = 0.f, gsB = 0.f, gs2B = 0.f;
#pragma unroll
  for (int mt = 0; mt < 4; ++mt) {
#pragma unroll
    for (int rg = 0; rg < 4; ++rg) {
      int row = mt*16 + lg*4 + rg;
      float v0 = acc2[mt][0][rg];
      float v1 = acc2[mt][1][rg];
      e[(rbase + row)*128 + col0]      = v0;
      e[(rbase + row)*128 + col0 + 16] = v1;
      if (do_stats) {
        gsA += v0;  gs2A += v0*v0;
        gsB += v1;  gs2B += v1*v1;
      }
    }
  }

  // ---- agg partial writeout ----
  av0 += __shfl_xor(av0, 16);  av0 += __shfl_xor(av0, 32);
  av1 += __shfl_xor(av1, 16);  av1 += __shfl_xor(av1, 32);
  if (l < 16) {
    aggP[(size_t)blk*128 + col0]      = av0;
    aggP[(size_t)blk*128 + col0 + 16] = av1;
  }

  // ---- GN stats (last layer): reduce to group sums, atomic to global ----
  if (do_stats) {
    gsA += __shfl_xor(gsA, 16);  gsA += __shfl_xor(gsA, 32);
    gsA += __shfl_xor(gsA, 1);   gsA += __shfl_xor(gsA, 2);
    gs2A += __shfl_xor(gs2A, 16); gs2A += __shfl_xor(gs2A, 32);
    gs2A += __shfl_xor(gs2A, 1);  gs2A += __shfl_xor(gs2A, 2);
    gsB += __shfl_xor(gsB, 16);  gsB += __shfl_xor(gsB, 32);
    gsB += __shfl_xor(gsB, 1);   gsB += __shfl_xor(gsB, 2);
    gs2B += __shfl_xor(gs2B, 16); gs2B += __shfl_xor(gs2B, 32);
    gs2B += __shfl_xor(gs2B, 1);  gs2B += __shfl_xor(gs2B, 2);
    if (l < 16 && (l & 3) == 0) {
      int g0 = col0 >> 2;
      atomicAdd(&sraw[((size_t)b*32 + g0)*2],     gsA);
      atomicAdd(&sraw[((size_t)b*32 + g0)*2 + 1], gs2A);
      int g1 = g0 + 4;
      atomicAdd(&sraw[((size_t)b*32 + g1)*2],     gsB);
      atomicAdd(&sraw[((size_t)b*32 + g1)*2 + 1], gs2B);
    }
  }
}

// ---------------- x update: x += relu(LN(Uh + agg)) ----------------
__global__ __launch_bounds__(128) void k_xupd(
    const float* __restrict__ aggP, const float* __restrict__ Uh,
    const float* __restrict__ lnh_s, const float* __restrict__ lnh_b,
    float* __restrict__ x) {
  int bi = blockIdx.x, d = threadIdx.x;
  float u = Uh[(size_t)bi*128 + d];
#pragma unroll
  for (int jt = 0; jt < 4; ++jt) u += aggP[((size_t)bi*4 + jt)*128 + d];
  float s = u, s2 = u*u;
#pragma unroll
  for (int m = 1; m <= 32; m <<= 1) { s += __shfl_xor(s, m); s2 += __shfl_xor(s2, m); }
  __shared__ float red[4];
  int wid = d >> 6;
  if ((d & 63) == 0) { red[wid] = s; red[2 + wid] = s2; }
  __syncthreads();
  s = red[0] + red[1];  s2 = red[2] + red[3];
  float mean = s * (1.f/128.f);
  float rs = rsqrtf(s2 * (1.f/128.f) - mean*mean + 1e-5f);
  x[(size_t)bi*128 + d] += fmaxf((u - mean)*rs*lnh_s[d] + lnh_b[d], 0.f);
}

// ---------------- zero the GN stats accumulators ----------------
__global__ __launch_bounds__(128) void k_zero(float* __restrict__ p) {
  p[threadIdx.x] = 0.f;
}

// ---------------- finalize GN stats ----------------
__global__ __launch_bounds__(64) void k_gnfin(
    const float* __restrict__ raw, float* __restrict__ stats) {
  int i = threadIdx.x;
  const float cnt = (float)(NN*NN*4);
  float S  = raw[i*2];
  float S2 = raw[i*2 + 1];
  float mean = S / cnt;
  float var = S2 / cnt - mean*mean;
  stats[i*2]     = mean;
  stats[i*2 + 1] = rsqrtf(var + 1e-5f);
}

// ---------------- final: out = relu(gn(e)) . conv_W + conv_b ----------------
__global__ __launch_bounds__(256) void k_out(
    const float* __restrict__ e, const float* __restrict__ stats,
    const float* __restrict__ gn_s, const float* __restrict__ gn_b,
    const float* __restrict__ convW, const float* __restrict__ convb,
    float* __restrict__ out) {
  int tid = threadIdx.x;
  int row = tid >> 2, part = tid & 3;
  size_t R = (size_t)blockIdx.x*64 + row;
  size_t b = R >> 16;
  float acc = 0.f;
  const float4* er = reinterpret_cast<const float4*>(e + R*128 + part*32);
#pragma unroll
  for (int q = 0; q < 8; ++q) {
    float4 f = er[q];
    float fv[4] = {f.x, f.y, f.z, f.w};
#pragma unroll
    for (int lidx = 0; lidx < 4; ++lidx) {
      int c = part*32 + q*4 + lidx;
      int g = c >> 2;
      float mean = stats[(b*NGROUP + g)*2 + 0];
      float rs   = stats[(b*NGROUP + g)*2 + 1];
      float t = (fv[lidx] - mean)*rs*gn_s[c] + gn_b[c];
      acc += fmaxf(t, 0.f) * convW[c];
    }
  }
  acc += __shfl_xor(acc, 1);
  acc += __shfl_xor(acc, 2);
  if (part == 0) out[R] = acc + convb[0];
}

extern "C" void kernel_launch(void* const* d_in, const int* in_sizes, int n_in,
                              void* d_out, int out_size, void* d_ws, size_t ws_size,
                              hipStream_t stream) {
  const float* coords  = (const float*)d_in[0];
  const float* adj_t   = (const float*)d_in[1];
  const float* t       = (const float*)d_in[2];
  const float* node_W  = (const float*)d_in[3];
  const float* node_b  = (const float*)d_in[4];
  const float* edge_W  = (const float*)d_in[5];
  const float* edge_b  = (const float*)d_in[6];
  const float* te1_W   = (const float*)d_in[7];
  const float* te1_b   = (const float*)d_in[8];
  const float* te2_W   = (const float*)d_in[9];
  const float* te2_b   = (const float*)d_in[10];
  const float* A_W     = (const float*)d_in[11];
  const float* A_b     = (const float*)d_in[12];
  const float* B_W     = (const float*)d_in[13];
  const float* B_b     = (const float*)d_in[14];
  const float* C_W     = (const float*)d_in[15];
  const float* C_b     = (const float*)d_in[16];
  const float* U_W     = (const float*)d_in[17];
  const float* U_b     = (const float*)d_in[18];
  const float* V_W     = (const float*)d_in[19];
  const float* V_b     = (const float*)d_in[20];
  const float* lnh_s   = (const float*)d_in[21];
  const float* lnh_b   = (const float*)d_in[22];
  const float* lne_s   = (const float*)d_in[23];
  const float* lne_b   = (const float*)d_in[24];
  const float* tl_W    = (const float*)d_in[25];
  const float* tl_b    = (const float*)d_in[26];
  const float* plo_ln_s= (const float*)d_in[27];
  const float* plo_ln_b= (const float*)d_in[28];
  const float* plo_W   = (const float*)d_in[29];
  const float* plo_b   = (const float*)d_in[30];
  const float* gn_s    = (const float*)d_in[31];
  const float* gn_b    = (const float*)d_in[32];
  const float* conv_W  = (const float*)d_in[33];
  const float* conv_b  = (const float*)d_in[34];

  float* ws    = (float*)d_ws;
  float* e     = ws;                        // 16,777,216 floats
  float* x     = e + (size_t)NROWS*128;
  float* Uh    = x + 65536;
  float* Vh    = Uh + 65536;
  float* Ax    = Vh + 65536;
  float* Bx    = Ax + 65536;
  float* tproj = Bx + 65536;                // 1024
  float* sraw  = tproj + 1024;              // 128
  float* stats = sraw + 128;                // 128
  float* aggP  = stats + 128;               // 262,144
  u16*   WTC   = (u16*)(aggP + 262144);     // 4*16384 u16 = 32768 float slots
  u16*   WTP   = WTC + (size_t)LL*16384;

  k_zero<<<1, 128, 0, stream>>>(sraw);
  k_wprep<<<512, 256, 0, stream>>>(C_W, plo_W, WTC, WTP);
  k_time<<<1, 128, 0, stream>>>(t, te1_W, te1_b, te2_W, te2_b, tl_W, tl_b, tproj);
  k_node_embed<<<8, 256, 0, stream>>>(coords, node_W, node_b, x);
  k_edge_embed<<<NROWS/64, 256, 0, stream>>>(adj_t, edge_W, edge_b, e);

  for (int i = 0; i < LL; ++i) {
    k_node4<<<BB*NN, 128, 0, stream>>>(x,
        U_W + (size_t)i*16384, U_b + i*128,
        V_W + (size_t)i*16384, V_b + i*128,
        A_W + (size_t)i*16384, A_b + i*128,
        B_W + (size_t)i*16384, B_b + i*128,
        Uh, Vh, Ax, Bx);
    k_layer<<<NROWS/64, 256, 0, stream>>>(e,
        WTC + (size_t)i*16384, WTP + (size_t)i*16384,
        C_b + i*128, Ax, Bx, Vh,
        lne_s + i*128, lne_b + i*128,
        tproj + i*BB*128,
        plo_ln_s + i*128, plo_ln_b + i*128, plo_b + i*128,
        aggP, sraw, (i == LL-1) ? 1 : 0);
    k_xupd<<<BB*NN, 128, 0, stream>>>(aggP, Uh, lnh_s + i*128, lnh_b + i*128, x);
  }

  k_gnfin<<<1, 64, 0, stream>>>(sraw, stats);
  k_out<<<NROWS/64, 256, 0, stream>>>(e, stats, gn_s, gn_b, conv_W, conv_b,
                                      (float*)d_out);
}

// Round 4
// 629.167 us; speedup vs baseline: 1.8279x; 1.2321x over previous
//
#include <hip/hip_runtime.h>
#include <hip/hip_bf16.h>

typedef unsigned short u16;
typedef __attribute__((ext_vector_type(8))) short short8;
typedef __attribute__((ext_vector_type(8))) unsigned short ushort8;
typedef __attribute__((ext_vector_type(4))) float f32x4;

#define BB 2
#define NN 256
#define DD 128
#define TDD 64
#define LL 4
#define NGROUP 32
#define NROWS (BB*NN*NN)      // 131072 edge rows
#define LDS_STR 68            // padded LDS stride for fp32 embed kernels

#define LOG1E4 9.210340371976184f
#define TWO_PI 6.283185307179586f

// ---------------- fp32 tile GEMM (embed kernels only) ----------------
#define TILE_GEMM(AT, WPTR, ACC) do {                                          \
  _Pragma("unroll 4")                                                          \
  for (int k = 0; k < 128; ++k) {                                              \
    const float4 w4 = *reinterpret_cast<const float4*>((WPTR) + k*128 + tx*4); \
    const float4 a0 = *reinterpret_cast<const float4*>(&(AT)[k*LDS_STR + ty*8]);     \
    const float4 a1 = *reinterpret_cast<const float4*>(&(AT)[k*LDS_STR + ty*8 + 4]); \
    const float av[8] = {a0.x,a0.y,a0.z,a0.w,a1.x,a1.y,a1.z,a1.w};             \
    const float wv[4] = {w4.x,w4.y,w4.z,w4.w};                                 \
    _Pragma("unroll") for (int r = 0; r < 8; ++r)                              \
      _Pragma("unroll") for (int c = 0; c < 4; ++c)                            \
        ACC[r][c] += av[r]*wv[c];                                              \
  }                                                                            \
} while (0)

__device__ __forceinline__ float sigmoidf_(float x) {
  return 1.f / (1.f + __expf(-x));
}

// round-to-nearest-even f32 -> bf16 bits
__device__ __forceinline__ u16 f2bf(float f) {
  union { float f; unsigned int u; } c; c.f = f;
  unsigned int r = (c.u + 0x7FFFu + ((c.u >> 16) & 1u)) >> 16;
  return (u16)r;
}

// ---------------- time embedding pipeline -> tproj[L][B][D] ----------------
__global__ __launch_bounds__(128) void k_time(
    const float* __restrict__ t,
    const float* __restrict__ te1_W, const float* __restrict__ te1_b,
    const float* __restrict__ te2_W, const float* __restrict__ te2_b,
    const float* __restrict__ tl_W,  const float* __restrict__ tl_b,
    float* __restrict__ tproj) {
  __shared__ float temb[128], h1[64], rt[64];
  int tid = threadIdx.x;
  for (int b = 0; b < BB; ++b) {
    float tv = t[b];
    {
      int j = tid & 63;
      float f = expf(-LOG1E4 * (float)j / 64.f);
      float a = tv * f;
      temb[tid] = (tid < 64) ? cosf(a) : sinf(a);
    }
    __syncthreads();
    if (tid < 64) {
      float acc = te1_b[tid];
      for (int k = 0; k < 128; ++k) acc += temb[k] * te1_W[k*64 + tid];
      h1[tid] = fmaxf(acc, 0.f);
    }
    __syncthreads();
    if (tid < 64) {
      float acc = te2_b[tid];
      for (int k = 0; k < 64; ++k) acc += h1[k] * te2_W[k*64 + tid];
      rt[tid] = fmaxf(acc, 0.f);   // relu(te)
    }
    __syncthreads();
    for (int i = 0; i < LL; ++i) {
      float acc = tl_b[i*128 + tid];
      for (int k = 0; k < 64; ++k) acc += rt[k] * tl_W[(i*64 + k)*128 + tid];
      tproj[(i*BB + b)*128 + tid] = acc;
    }
    __syncthreads();
  }
}

// ---------------- node pos-embed + node_W GEMM -> x (512 x 128) ----------------
__global__ __launch_bounds__(256) void k_node_embed(
    const float* __restrict__ coords, const float* __restrict__ W,
    const float* __restrict__ bias, float* __restrict__ x_out) {
  __shared__ float at[128*LDS_STR];
  int tid = threadIdx.x;
  int row = tid >> 2, part = tid & 3;
  int R = blockIdx.x*64 + row;
  float cy = coords[R*2 + 0], cx = coords[R*2 + 1];
#pragma unroll
  for (int q = 0; q < 32; ++q) {
    int c = part*32 + q;
    int k = (c < 64) ? c : c - 64;
    float v = (c < 64) ? cy : cx;
    int m = k >> 1;
    float inv = expf(-LOG1E4 * (float)m / 32.f);
    float a = v * TWO_PI * inv;
    at[c*LDS_STR + row] = (k & 1) ? cosf(a) : sinf(a);
  }
  __syncthreads();
  int tx = tid & 31, ty = tid >> 5;
  float acc[8][4] = {};
  TILE_GEMM(at, W, acc);
  float4 bb4 = *reinterpret_cast<const float4*>(bias + tx*4);
#pragma unroll
  for (int r = 0; r < 8; ++r) {
    int R2 = blockIdx.x*64 + ty*8 + r;
    float4 o = {acc[r][0]+bb4.x, acc[r][1]+bb4.y, acc[r][2]+bb4.z, acc[r][3]+bb4.w};
    *reinterpret_cast<float4*>(x_out + (size_t)R2*128 + tx*4) = o;
  }
}

// ---------------- edge pos-embed + edge_W GEMM -> e (131072 x 128) ----------------
__global__ __launch_bounds__(256) void k_edge_embed(
    const float* __restrict__ adj, const float* __restrict__ W,
    const float* __restrict__ bias, float* __restrict__ e_out) {
  __shared__ float at[128*LDS_STR];
  int tid = threadIdx.x;
  int row = tid >> 2, part = tid & 3;
  size_t R = (size_t)blockIdx.x*64 + row;
  float v = adj[R];
#pragma unroll
  for (int q = 0; q < 32; ++q) {
    int k = part*32 + q;
    int m = k >> 1;
    float inv = expf(-LOG1E4 * (float)m / 64.f);
    float a = v * inv;
    at[k*LDS_STR + row] = (k & 1) ? cosf(a) : sinf(a);
  }
  __syncthreads();
  int tx = tid & 31, ty = tid >> 5;
  float acc[8][4] = {};
  TILE_GEMM(at, W, acc);
  float4 bb4 = *reinterpret_cast<const float4*>(bias + tx*4);
#pragma unroll
  for (int r = 0; r < 8; ++r) {
    size_t R2 = (size_t)blockIdx.x*64 + ty*8 + r;
    float4 o = {acc[r][0]+bb4.x, acc[r][1]+bb4.y, acc[r][2]+bb4.z, acc[r][3]+bb4.w};
    *reinterpret_cast<float4*>(e_out + R2*128 + tx*4) = o;
  }
}

// ---------------- per-layer node linears: Uh,Vh,Ax,Bx (512 rows) ----------------
__global__ __launch_bounds__(128) void k_node4(
    const float* __restrict__ x,
    const float* __restrict__ UW, const float* __restrict__ Ub,
    const float* __restrict__ VW, const float* __restrict__ Vb,
    const float* __restrict__ AW, const float* __restrict__ Ab,
    const float* __restrict__ BW, const float* __restrict__ Bb,
    float* __restrict__ Uh, float* __restrict__ Vh,
    float* __restrict__ Axo, float* __restrict__ Bxo) {
  __shared__ float xr[128];
  int R = blockIdx.x, d = threadIdx.x;
  xr[d] = x[(size_t)R*128 + d];
  __syncthreads();
  float au = Ub[d], av = Vb[d], aa = Ab[d], ab = Bb[d];
  for (int k = 0; k < 128; ++k) {
    float xv = xr[k];
    au += xv * UW[k*128 + d];
    av += xv * VW[k*128 + d];
    aa += xv * AW[k*128 + d];
    ab += xv * BW[k*128 + d];
  }
  Uh[(size_t)R*128 + d] = au;
  Vh[(size_t)R*128 + d] = av;
  Axo[(size_t)R*128 + d] = aa;
  Bxo[(size_t)R*128 + d] = ab;
}

// ---------------- weight prep: bf16 transposed copies WT[n][k] ----------------
__global__ __launch_bounds__(256) void k_wprep(
    const float* __restrict__ CW, const float* __restrict__ PW,
    u16* __restrict__ WTC, u16* __restrict__ WTP) {
  int idx = blockIdx.x*256 + threadIdx.x;    // 0..131071
  int m = idx >> 14;                          // 0..7 (layer*2 + type)
  int r = idx & 16383;
  int layer = m >> 1;
  int n = r >> 7, k = r & 127;
  if ((m & 1) == 0)
    WTC[layer*16384 + n*128 + k] = f2bf(CW[(size_t)layer*16384 + k*128 + n]);
  else
    WTP[layer*16384 + n*128 + k] = f2bf(PW[(size_t)layer*16384 + k*128 + n]);
}

// ================= fused per-layer MFMA kernel (wave-independent strips) =====
// grid = 2048 blocks x 256 thr. Block = (bi, jt): 64 edge rows. Wave w owns
// rows w*16..w*16+15 x ALL 128 cols. All LN/elementwise wave-internal.
// LDS: Abuf 16KB (bf16 A-operand, per-wave strips, XOR-swizzled) + aggW 2KB.
__global__ __launch_bounds__(256) void k_layer(
    float* __restrict__ e,
    const u16* __restrict__ WTC, const u16* __restrict__ WTP,
    const float* __restrict__ Cb, const float* __restrict__ Ax,
    const float* __restrict__ Bx, const float* __restrict__ Vh,
    const float* __restrict__ lnes_g, const float* __restrict__ lneb_g,
    const float* __restrict__ tp_g,
    const float* __restrict__ plos_g, const float* __restrict__ plobl_g,
    const float* __restrict__ plob_g,
    float* __restrict__ aggP) {

  __shared__ __align__(16) u16  Abuf[64*128];   // 16 KB
  __shared__ float aggW[4][128];                // 2 KB

  const int tid = threadIdx.x;
  const int blk = blockIdx.x;
  const int bi = blk >> 2;          // b*256 + i
  const int b  = bi >> 8;
  const int jt = blk & 3;
  const size_t rbase = (size_t)bi*256 + jt*64;

  const int w  = tid >> 6;
  const int l  = tid & 63;
  const int lg = l >> 4;            // 0..3
  const int ln = l & 15;            // 0..15

  // ---- stage e strip -> bf16 LDS (chunk ^ (row&7) swizzle) ----
  {
    const int r = tid >> 2;         // 0..63 ; wave w covers rows w*16..+15
    const int p = tid & 3;
    const float* src = e + (rbase + r)*128 + p*32;
    const int r7 = r & 7;
    u16* arow = Abuf + r*128;
#pragma unroll
    for (int q = 0; q < 4; ++q) {
      float4 f0 = *reinterpret_cast<const float4*>(src + q*8);
      float4 f1 = *reinterpret_cast<const float4*>(src + q*8 + 4);
      int pc = (p*4 + q) ^ r7;
      ushort8 h = {f2bf(f0.x),f2bf(f0.y),f2bf(f0.z),f2bf(f0.w),
                   f2bf(f1.x),f2bf(f1.y),f2bf(f1.z),f2bf(f1.w)};
      *reinterpret_cast<ushort8*>(arow + pc*8) = h;
    }
  }
  __syncthreads();

  const int jrow0 = jt*64 + w*16 + lg*4;      // first j-row of lane's 4 rows
  const int myrow = w*16 + lg*4;              // within 64-row tile

  // ---- acc init: gate = Cb + Ax[i] + Bx[j]  (GEMM adds e@C_W) ----
  f32x4 acc[8];
#pragma unroll
  for (int nt = 0; nt < 8; ++nt) {
    const int c = nt*16 + ln;
    const float cbax = Cb[c] + Ax[(size_t)bi*128 + c];
#pragma unroll
    for (int rg = 0; rg < 4; ++rg)
      acc[nt][rg] = cbax + Bx[((size_t)b*256 + jrow0 + rg)*128 + c];
  }

  // ---- GEMM1: += e @ C_W ----
  {
    const u16* arow = Abuf + (w*16 + ln)*128;
    const int r7 = ln & 7;
#pragma unroll
    for (int ks = 0; ks < 4; ++ks) {
      short8 a = *reinterpret_cast<const short8*>(arow + (((ks*4 + lg) ^ r7) << 3));
#pragma unroll
      for (int nt = 0; nt < 8; ++nt) {
        short8 bw = *reinterpret_cast<const short8*>(
            WTC + (nt*16 + ln)*128 + ks*32 + lg*8);
        acc[nt] = __builtin_amdgcn_mfma_f32_16x16x32_bf16(a, bw, acc[nt], 0, 0, 0);
      }
    }
  }

  // ---- per-row pipeline: agg, LN1+relu+tproj, LN2+silu -> sv to LDS ----
  float av[8] = {0.f,0.f,0.f,0.f,0.f,0.f,0.f,0.f};
  float tp_[8], ls_[8], lb_[8], ps_[8], pl_[8];
#pragma unroll
  for (int nt = 0; nt < 8; ++nt) {
    const int c = nt*16 + ln;
    tp_[nt] = tp_g[b*128 + c];
    ls_[nt] = lnes_g[c];  lb_[nt] = lneb_g[c];
    ps_[nt] = plos_g[c];  pl_[nt] = plobl_g[c];
  }

#pragma unroll
  for (int rg = 0; rg < 4; ++rg) {
    // LN1 row stats (in-lane over nt, then 16-lane group reduce)
    float s = 0.f, s2 = 0.f;
#pragma unroll
    for (int nt = 0; nt < 8; ++nt) { float g = acc[nt][rg]; s += g; s2 += g*g; }
    s += __shfl_xor(s, 1);  s2 += __shfl_xor(s2, 1);
    s += __shfl_xor(s, 2);  s2 += __shfl_xor(s2, 2);
    s += __shfl_xor(s, 4);  s2 += __shfl_xor(s2, 4);
    s += __shfl_xor(s, 8);  s2 += __shfl_xor(s2, 8);
    const float mean = s * (1.f/128.f);
    const float rs = rsqrtf(s2 * (1.f/128.f) - mean*mean + 1e-5f);
    // agg + LN1 apply + relu + tproj
    const size_t vrow = ((size_t)b*256 + jrow0 + rg)*128;
    float s3 = 0.f, s4 = 0.f;
#pragma unroll
    for (int nt = 0; nt < 8; ++nt) {
      const float g = acc[nt][rg];
      av[nt] += Vh[vrow + nt*16 + ln] * sigmoidf_(g);
      float tv = fmaxf((g - mean)*rs*ls_[nt] + lb_[nt], 0.f) + tp_[nt];
      acc[nt][rg] = tv;
      s3 += tv;  s4 += tv*tv;
    }
    // LN2 row stats
    s3 += __shfl_xor(s3, 1);  s4 += __shfl_xor(s4, 1);
    s3 += __shfl_xor(s3, 2);  s4 += __shfl_xor(s4, 2);
    s3 += __shfl_xor(s3, 4);  s4 += __shfl_xor(s4, 4);
    s3 += __shfl_xor(s3, 8);  s4 += __shfl_xor(s4, 8);
    const float mean2 = s3 * (1.f/128.f);
    const float rs2 = rsqrtf(s4 * (1.f/128.f) - mean2*mean2 + 1e-5f);
    // LN2 apply + silu -> Abuf (bf16 swizzled)
    const int rr = myrow + rg;
    const int rr7 = rr & 7;
#pragma unroll
    for (int nt = 0; nt < 8; ++nt) {
      float vv = (acc[nt][rg] - mean2)*rs2*ps_[nt] + pl_[nt];
      vv = vv * sigmoidf_(vv);
      const int cc = nt*16 + ln;
      const int pc = (cc >> 3) ^ rr7;
      Abuf[rr*128 + pc*8 + (cc & 7)] = f2bf(vv);
    }
  }

  // ---- e residual loads (L2-hot) for GEMM2 init ----
  float ein[8][4];
#pragma unroll
  for (int nt = 0; nt < 8; ++nt)
#pragma unroll
    for (int rg = 0; rg < 4; ++rg)
      ein[nt][rg] = e[(rbase + myrow + rg)*128 + nt*16 + ln];

  __syncthreads();

  // ---- GEMM2: e = e_in + sv @ plo_W + plo_b ----
  f32x4 acc2[8];
#pragma unroll
  for (int nt = 0; nt < 8; ++nt) {
    const float pbv = plob_g[nt*16 + ln];
#pragma unroll
    for (int rg = 0; rg < 4; ++rg)
      acc2[nt][rg] = ein[nt][rg] + pbv;
  }
  {
    const u16* arow = Abuf + (w*16 + ln)*128;
    const int r7 = ln & 7;
#pragma unroll
    for (int ks = 0; ks < 4; ++ks) {
      short8 a = *reinterpret_cast<const short8*>(arow + (((ks*4 + lg) ^ r7) << 3));
#pragma unroll
      for (int nt = 0; nt < 8; ++nt) {
        short8 bw = *reinterpret_cast<const short8*>(
            WTP + (nt*16 + ln)*128 + ks*32 + lg*8);
        acc2[nt] = __builtin_amdgcn_mfma_f32_16x16x32_bf16(a, bw, acc2[nt], 0, 0, 0);
      }
    }
  }
#pragma unroll
  for (int nt = 0; nt < 8; ++nt)
#pragma unroll
    for (int rg = 0; rg < 4; ++rg)
      e[(rbase + myrow + rg)*128 + nt*16 + ln] = acc2[nt][rg];

  // ---- agg: reduce over wave's 16 rows, then block-combine ----
#pragma unroll
  for (int nt = 0; nt < 8; ++nt) {
    float v = av[nt];
    v += __shfl_xor(v, 16);
    v += __shfl_xor(v, 32);
    av[nt] = v;
  }
  if (l < 16) {
#pragma unroll
    for (int nt = 0; nt < 8; ++nt)
      aggW[w][nt*16 + ln] = av[nt];
  }
  __syncthreads();
  if (tid < 128)
    aggP[(size_t)blk*128 + tid] =
        aggW[0][tid] + aggW[1][tid] + aggW[2][tid] + aggW[3][tid];
}

// ---------------- x update: x += relu(LN(Uh + agg)) ----------------
__global__ __launch_bounds__(128) void k_xupd(
    const float* __restrict__ aggP, const float* __restrict__ Uh,
    const float* __restrict__ lnh_s, const float* __restrict__ lnh_b,
    float* __restrict__ x) {
  int bi = blockIdx.x, d = threadIdx.x;
  float u = Uh[(size_t)bi*128 + d];
#pragma unroll
  for (int jt = 0; jt < 4; ++jt) u += aggP[((size_t)bi*4 + jt)*128 + d];
  float s = u, s2 = u*u;
#pragma unroll
  for (int m = 1; m <= 32; m <<= 1) { s += __shfl_xor(s, m); s2 += __shfl_xor(s2, m); }
  __shared__ float red[4];
  int wid = d >> 6;
  if ((d & 63) == 0) { red[wid] = s; red[2 + wid] = s2; }
  __syncthreads();
  s = red[0] + red[1];  s2 = red[2] + red[3];
  float mean = s * (1.f/128.f);
  float rs = rsqrtf(s2 * (1.f/128.f) - mean*mean + 1e-5f);
  x[(size_t)bi*128 + d] += fmaxf((u - mean)*rs*lnh_s[d] + lnh_b[d], 0.f);
}

// ---------------- zero the GN stats accumulators ----------------
__global__ __launch_bounds__(128) void k_zero(float* __restrict__ p) {
  p[threadIdx.x] = 0.f;
}

// ---------- GN stats, group-aligned: one float4 = one group ----------
__global__ __launch_bounds__(256) void k_gnstats2(
    const float* __restrict__ e, float* __restrict__ sraw) {
  const int blk = blockIdx.x;      // 512 blocks x 256 rows
  const int b = blk >> 8;
  const int c = threadIdx.x & 31;  // group == float4 chunk
  const int r0 = threadIdx.x >> 5; // 0..7
  float s = 0.f, s2 = 0.f;
  for (int it = 0; it < 32; ++it) {
    size_t row = (size_t)blk*256 + it*8 + r0;
    float4 f = *reinterpret_cast<const float4*>(e + row*128 + c*4);
    s  += f.x + f.y + f.z + f.w;
    s2 += f.x*f.x + f.y*f.y + f.z*f.z + f.w*f.w;
  }
  __shared__ float red[256], red2[256];
  red[threadIdx.x] = s;  red2[threadIdx.x] = s2;
  __syncthreads();
  if (threadIdx.x < 32) {
    float S = 0.f, S2 = 0.f;
#pragma unroll
    for (int k = 0; k < 8; ++k) { S += red[k*32 + threadIdx.x]; S2 += red2[k*32 + threadIdx.x]; }
    atomicAdd(&sraw[((size_t)b*32 + threadIdx.x)*2],     S);
    atomicAdd(&sraw[((size_t)b*32 + threadIdx.x)*2 + 1], S2);
  }
}

// ---------------- finalize GN stats ----------------
__global__ __launch_bounds__(64) void k_gnfin(
    const float* __restrict__ raw, float* __restrict__ stats) {
  int i = threadIdx.x;
  const float cnt = (float)(NN*NN*4);
  float S  = raw[i*2];
  float S2 = raw[i*2 + 1];
  float mean = S / cnt;
  float var = S2 / cnt - mean*mean;
  stats[i*2]     = mean;
  stats[i*2 + 1] = rsqrtf(var + 1e-5f);
}

// ---------------- final: out = relu(gn(e)) . conv_W + conv_b ----------------
__global__ __launch_bounds__(256) void k_out(
    const float* __restrict__ e, const float* __restrict__ stats,
    const float* __restrict__ gn_s, const float* __restrict__ gn_b,
    const float* __restrict__ convW, const float* __restrict__ convb,
    float* __restrict__ out) {
  int tid = threadIdx.x;
  int row = tid >> 2, part = tid & 3;
  size_t R = (size_t)blockIdx.x*64 + row;
  size_t b = R >> 16;
  float acc = 0.f;
  const float4* er = reinterpret_cast<const float4*>(e + R*128 + part*32);
#pragma unroll
  for (int q = 0; q < 8; ++q) {
    float4 f = er[q];
    float fv[4] = {f.x, f.y, f.z, f.w};
#pragma unroll
    for (int lidx = 0; lidx < 4; ++lidx) {
      int c = part*32 + q*4 + lidx;
      int g = c >> 2;
      float mean = stats[(b*NGROUP + g)*2 + 0];
      float rs   = stats[(b*NGROUP + g)*2 + 1];
      float t = (fv[lidx] - mean)*rs*gn_s[c] + gn_b[c];
      acc += fmaxf(t, 0.f) * convW[c];
    }
  }
  acc += __shfl_xor(acc, 1);
  acc += __shfl_xor(acc, 2);
  if (part == 0) out[R] = acc + convb[0];
}

extern "C" void kernel_launch(void* const* d_in, const int* in_sizes, int n_in,
                              void* d_out, int out_size, void* d_ws, size_t ws_size,
                              hipStream_t stream) {
  const float* coords  = (const float*)d_in[0];
  const float* adj_t   = (const float*)d_in[1];
  const float* t       = (const float*)d_in[2];
  const float* node_W  = (const float*)d_in[3];
  const float* node_b  = (const float*)d_in[4];
  const float* edge_W  = (const float*)d_in[5];
  const float* edge_b  = (const float*)d_in[6];
  const float* te1_W   = (const float*)d_in[7];
  const float* te1_b   = (const float*)d_in[8];
  const float* te2_W   = (const float*)d_in[9];
  const float* te2_b   = (const float*)d_in[10];
  const float* A_W     = (const float*)d_in[11];
  const float* A_b     = (const float*)d_in[12];
  const float* B_W     = (const float*)d_in[13];
  const float* B_b     = (const float*)d_in[14];
  const float* C_W     = (const float*)d_in[15];
  const float* C_b     = (const float*)d_in[16];
  const float* U_W     = (const float*)d_in[17];
  const float* U_b     = (const float*)d_in[18];
  const float* V_W     = (const float*)d_in[19];
  const float* V_b     = (const float*)d_in[20];
  const float* lnh_s   = (const float*)d_in[21];
  const float* lnh_b   = (const float*)d_in[22];
  const float* lne_s   = (const float*)d_in[23];
  const float* lne_b   = (const float*)d_in[24];
  const float* tl_W    = (const float*)d_in[25];
  const float* tl_b    = (const float*)d_in[26];
  const float* plo_ln_s= (const float*)d_in[27];
  const float* plo_ln_b= (const float*)d_in[28];
  const float* plo_W   = (const float*)d_in[29];
  const float* plo_b   = (const float*)d_in[30];
  const float* gn_s    = (const float*)d_in[31];
  const float* gn_b    = (const float*)d_in[32];
  const float* conv_W  = (const float*)d_in[33];
  const float* conv_b  = (const float*)d_in[34];

  float* ws    = (float*)d_ws;
  float* e     = ws;                        // 16,777,216 floats
  float* x     = e + (size_t)NROWS*128;
  float* Uh    = x + 65536;
  float* Vh    = Uh + 65536;
  float* Ax    = Vh + 65536;
  float* Bx    = Ax + 65536;
  float* tproj = Bx + 65536;                // 1024
  float* sraw  = tproj + 1024;              // 128
  float* stats = sraw + 128;                // 128
  float* aggP  = stats + 128;               // 262,144
  u16*   WTC   = (u16*)(aggP + 262144);     // 4*16384 u16
  u16*   WTP   = WTC + (size_t)LL*16384;

  k_zero<<<1, 128, 0, stream>>>(sraw);
  k_wprep<<<512, 256, 0, stream>>>(C_W, plo_W, WTC, WTP);
  k_time<<<1, 128, 0, stream>>>(t, te1_W, te1_b, te2_W, te2_b, tl_W, tl_b, tproj);
  k_node_embed<<<8, 256, 0, stream>>>(coords, node_W, node_b, x);
  k_edge_embed<<<NROWS/64, 256, 0, stream>>>(adj_t, edge_W, edge_b, e);

  for (int i = 0; i < LL; ++i) {
    k_node4<<<BB*NN, 128, 0, stream>>>(x,
        U_W + (size_t)i*16384, U_b + i*128,
        V_W + (size_t)i*16384, V_b + i*128,
        A_W + (size_t)i*16384, A_b + i*128,
        B_W + (size_t)i*16384, B_b + i*128,
        Uh, Vh, Ax, Bx);
    k_layer<<<NROWS/64, 256, 0, stream>>>(e,
        WTC + (size_t)i*16384, WTP + (size_t)i*16384,
        C_b + i*128, Ax, Bx, Vh,
        lne_s + i*128, lne_b + i*128,
        tproj + i*BB*128,
        plo_ln_s + i*128, plo_ln_b + i*128, plo_b + i*128,
        aggP);
    k_xupd<<<BB*NN, 128, 0, stream>>>(aggP, Uh, lnh_s + i*128, lnh_b + i*128, x);
  }

  k_gnstats2<<<512, 256, 0, stream>>>(e, sraw);
  k_gnfin<<<1, 64, 0, stream>>>(sraw, stats);
  k_out<<<NROWS/64, 256, 0, stream>>>(e, stats, gn_s, gn_b, conv_W, conv_b,
                                      (float*)d_out);
}